// Round 14
// baseline (2091.825 us; speedup 1.0000x reference)
//
#include <hip/hip_runtime.h>
#include <hip/hip_bf16.h>

#define B 4
#define S 128
#define D 1024
#define NS 4
#define KF 8
#define LNUM 3
#define DFF 3072
#define ND 4096
#define T 1024          // S*KF
#define TB 4096         // T*B
#define VOCABSZ 6144
#define SINKIT 20

typedef unsigned short u16;
typedef __attribute__((ext_vector_type(8))) short short8;
typedef __attribute__((ext_vector_type(4))) float f32x4;

__device__ __forceinline__ void gload16(const void* g, void* l) {
  __builtin_amdgcn_global_load_lds(
      (const __attribute__((address_space(1))) void*)g,
      (__attribute__((address_space(3))) void*)l, 16, 0, 0);
}

// sinkhorn + softmax helper (device, thread-0 of a block)
__device__ __forceinline__ void sink_compute(const float* Hl, const float* wpre,
                                             float* Pout /*[20] LDS*/) {
  float M[16];
  for (int i = 0; i < 16; ++i) M[i] = expf(Hl[i]);
  for (int it = 0; it < SINKIT; ++it) {
    for (int m = 0; m < 4; ++m) {
      float s = M[m*4+0] + M[m*4+1] + M[m*4+2] + M[m*4+3];
      for (int n = 0; n < 4; ++n) M[m*4+n] /= s;
    }
    for (int n = 0; n < 4; ++n) {
      float s = M[0*4+n] + M[1*4+n] + M[2*4+n] + M[3*4+n];
      for (int m = 0; m < 4; ++m) M[m*4+n] /= s;
    }
  }
  for (int i = 0; i < 16; ++i) Pout[i] = M[i];
  float a[4];
  float mx = fmaxf(fmaxf(wpre[0], wpre[1]), fmaxf(wpre[2], wpre[3]));
  float sm = 0.f;
  for (int i = 0; i < 4; ++i) { a[i] = expf(wpre[i] - mx); sm += a[i]; }
  for (int i = 0; i < 4; ++i) Pout[16+i] = a[i] / sm;
}

// ---------------- embed gather ----------------
__global__ __launch_bounds__(256)
void gather_kernel(const int* __restrict__ tok, const float* __restrict__ embed,
                   float* __restrict__ h) {
  const int idx = blockIdx.x * 256 + threadIdx.x;
  const int d   = idx % D;
  const int sbn = idx / D;
  const int sb  = sbn / NS;
  const int b   = sb % B, s = sb / B;
  h[idx] = embed[(size_t)tok[b*S + s] * D + d];
}

// ---------------- stream mix (sinkhorn folded in) ----------------
__global__ __launch_bounds__(256)
void mix_kernel(const float* __restrict__ h, const float* __restrict__ Hl,
                const float* __restrict__ wpre,
                float* __restrict__ h_mix, float* __restrict__ x) {
  __shared__ float P[20];
  if (threadIdx.x == 0) sink_compute(Hl, wpre, P);
  __syncthreads();
  const int idx = blockIdx.x * 256 + threadIdx.x;
  const int d = idx % D, sb = idx / D;
  const float* hp = h + (size_t)sb * NS * D + d;
  const float h0 = hp[0], h1 = hp[D], h2 = hp[2*D], h3 = hp[3*D];
  float xv = 0.f;
  #pragma unroll
  for (int m = 0; m < 4; ++m) {
    float hm = P[m*4+0]*h0 + P[m*4+1]*h1 + P[m*4+2]*h2 + P[m*4+3]*h3;
    h_mix[(size_t)sb * NS * D + m*D + d] = hm;
    xv = fmaf(P[16+m], hm, xv);
  }
  x[idx] = xv;
}

// ---------------- PLIF scan -> binary bf16 spikes (manual reg pipeline, PF=64) --------
template<bool R1, bool A2>
__global__ __launch_bounds__(256)
void plif_kernel(const float* __restrict__ z1, const float* __restrict__ z2,
                 const float* __restrict__ beta, const float* __restrict__ vth,
                 u16* __restrict__ outp, int C) {
  const int idx = blockIdx.x * 256 + threadIdx.x;
  const int c = idx % C;
  const int stride = B * C;
  const float be = beta[c], vt = vth[c], omb = 1.f - be;
  float v = 0.f;
  constexpr int PF = 64;
  float xA[R1 ? PF/8 : PF], yA[A2 ? PF : 1];
  float xB[R1 ? PF/8 : PF], yB[A2 ? PF : 1];

#define PLOAD(xa, ya, tb) do {                                               \
    if (R1) {                                                                \
      _Pragma("unroll")                                                      \
      for (int i = 0; i < PF/8; ++i)                                         \
        xa[i] = z1[(size_t)((tb)/8 + i) * stride + idx];                     \
    } else {                                                                 \
      _Pragma("unroll")                                                      \
      for (int i = 0; i < PF; ++i)                                           \
        xa[i] = z1[(size_t)((tb) + i) * stride + idx];                       \
    }                                                                        \
    if (A2) {                                                                \
      _Pragma("unroll")                                                      \
      for (int i = 0; i < PF; ++i)                                           \
        ya[i] = z2[(size_t)((tb) + i) * stride + idx];                       \
    }                                                                        \
  } while (0)

#define PCOMP(xa, ya, tb) do {                                               \
    _Pragma("unroll")                                                        \
    for (int i = 0; i < PF; ++i) {                                           \
      float xt = R1 ? xa[i >> 3] : xa[i];                                    \
      if (A2) xt += ya[i];                                                   \
      v = fmaf(be, v, omb * xt);                                             \
      const bool sp = (v >= vt);                                             \
      if (sp) v -= vt;                                                       \
      outp[(size_t)((tb) + i) * stride + idx] = sp ? (u16)0x3F80 : (u16)0;   \
    }                                                                        \
  } while (0)

  PLOAD(xA, yA, 0);
  for (int tb = 0; tb < T; tb += 2*PF) {
    PLOAD(xB, yB, tb + PF);
    PCOMP(xA, yA, tb);
    if (tb + 2*PF < T) PLOAD(xA, yA, tb + 2*PF);
    PCOMP(xB, yB, tb + PF);
  }
#undef PLOAD
#undef PCOMP
}

// ---------------- fused gate+up PLIF from fused z12 [t][b][6144] (PF=32) --------------
__global__ __launch_bounds__(256)
void plif_gu_kernel(const float* __restrict__ z12,
                    const float* __restrict__ bg, const float* __restrict__ vg_,
                    const float* __restrict__ bu, const float* __restrict__ vu_,
                    u16* __restrict__ outp) {
  const int idx = blockIdx.x * 256 + threadIdx.x;   // over B*DFF
  const int c = idx % DFF, b = idx / DFF;
  const float beg = bg[c], vtg = vg_[c], beu = bu[c], vtu = vu_[c];
  const float og = 1.f - beg, ou = 1.f - beu;
  float vg = 0.f, vu = 0.f;
  constexpr int PF = 32;
  float gA[PF], uA[PF], gB[PF], uB[PF];

#define GLOAD_(ga, ua, tb) do {                                              \
    _Pragma("unroll")                                                        \
    for (int i = 0; i < PF; ++i) {                                           \
      const size_t off_ = ((size_t)((tb) + i) * B + b) * (2*DFF) + c;        \
      ga[i] = z12[off_];                                                     \
      ua[i] = z12[off_ + DFF];                                               \
    }                                                                        \
  } while (0)

#define GCOMP_(ga, ua, tb) do {                                              \
    _Pragma("unroll")                                                        \
    for (int i = 0; i < PF; ++i) {                                           \
      vg = fmaf(beg, vg, og * ga[i]);                                        \
      vu = fmaf(beu, vu, ou * ua[i]);                                        \
      const bool sg = (vg >= vtg), su = (vu >= vtu);                         \
      if (sg) vg -= vtg;                                                     \
      if (su) vu -= vtu;                                                     \
      outp[(size_t)((tb) + i) * (B*DFF) + idx] = (sg && su) ? (u16)0x3F80 : (u16)0; \
    }                                                                        \
  } while (0)

  GLOAD_(gA, uA, 0);
  for (int tb = 0; tb < T; tb += 2*PF) {
    GLOAD_(gB, uB, tb + PF);
    GCOMP_(gA, uA, tb);
    if (tb + 2*PF < T) GLOAD_(gA, uA, tb + 2*PF);
    GCOMP_(gB, uB, tb + PF);
  }
#undef GLOAD_
#undef GCOMP_
}

// ---------------- weight prep: transpose + scale + bf16 hi/lo split -> [N][2K] ----------------
__global__ __launch_bounds__(256)
void prep_t_kernel(const float* __restrict__ W, const float* __restrict__ sA,
                   const float* __restrict__ sB, float mult,
                   u16* __restrict__ wt, int Kd, int Nd) {
  __shared__ float tile[64][65];
  const int tid = threadIdx.x;
  const int bn = blockIdx.x, bk = blockIdx.y;
  const int c = tid & 63, r0 = (tid >> 6) * 16;
  #pragma unroll
  for (int i = 0; i < 16; ++i) {
    const int r = r0 + i;
    const int kg = bk*64 + r;
    float s = mult;
    if (sA) s *= sA[kg];
    if (sB) s *= sB[kg];
    tile[r][c] = W[(size_t)kg * Nd + bn*64 + c] * s;
  }
  __syncthreads();
  const int K2 = 2 * Kd;
  #pragma unroll
  for (int i = 0; i < 16; ++i) {
    const int nl = r0 + i;
    const float v = tile[c][nl];
    const __hip_bfloat16 h = __float2bfloat16(v);
    const size_t off = (size_t)(bn*64 + nl) * K2 + bk*64 + c;
    wt[off] = *(const u16*)&h;
    const __hip_bfloat16 lo = __float2bfloat16(v - __bfloat162float(h));
    wt[off + Kd] = *(const u16*)&lo;
  }
}

// ---------------- paired prep (gate|up in one launch, blockIdx.z selects) ----------------
__global__ __launch_bounds__(256)
void prep_t2_kernel(const float* __restrict__ W0, const float* __restrict__ W1,
                    const float* __restrict__ sA,
                    u16* __restrict__ wt0, u16* __restrict__ wt1, int Kd, int Nd) {
  const float* W = blockIdx.z ? W1 : W0;
  u16* wt = blockIdx.z ? wt1 : wt0;
  __shared__ float tile[64][65];
  const int tid = threadIdx.x;
  const int bn = blockIdx.x, bk = blockIdx.y;
  const int c = tid & 63, r0 = (tid >> 6) * 16;
  #pragma unroll
  for (int i = 0; i < 16; ++i) {
    const int r = r0 + i;
    const int kg = bk*64 + r;
    tile[r][c] = W[(size_t)kg * Nd + bn*64 + c] * sA[kg];
  }
  __syncthreads();
  const int K2 = 2 * Kd;
  #pragma unroll
  for (int i = 0; i < 16; ++i) {
    const int nl = r0 + i;
    const float v = tile[c][nl];
    const __hip_bfloat16 h = __float2bfloat16(v);
    const size_t off = (size_t)(bn*64 + nl) * K2 + bk*64 + c;
    wt[off] = *(const u16*)&h;
    const __hip_bfloat16 lo = __float2bfloat16(v - __bfloat162float(h));
    wt[off + Kd] = *(const u16*)&lo;
  }
}

// ---------------- prep (no transpose): W [Nd][Kd] -> wt [Nd][2Kd] hi|lo ----------------
__global__ __launch_bounds__(256)
void prep_nt_kernel(const float* __restrict__ W, const float* __restrict__ sK, float mult,
                    u16* __restrict__ wt, int Kd) {
  const size_t idx = (size_t)blockIdx.x * 256 + threadIdx.x;
  const int k = (int)(idx % Kd);
  const size_t n = idx / Kd;
  const float v = W[idx] * mult * (sK ? sK[k] : 1.f);
  const __hip_bfloat16 h = __float2bfloat16(v);
  const size_t off = n * (2*Kd) + k;
  wt[off] = *(const u16*)&h;
  const __hip_bfloat16 lo = __float2bfloat16(v - __bfloat162float(h));
  wt[off + Kd] = *(const u16*)&lo;
}

// ---------------- deterministic 4-way partial reduce ----------------
template<bool ADDC>
__global__ __launch_bounds__(256)
void reduce4_kernel(float* __restrict__ out, const float* __restrict__ p, size_t n) {
  const size_t i = ((size_t)blockIdx.x * 256 + threadIdx.x) * 4;
  float4 a = *(const float4*)(p + i);
  float4 b = *(const float4*)(p + n + i);
  float4 c = *(const float4*)(p + 2*n + i);
  float4 d = *(const float4*)(p + 3*n + i);
  float4 o;
  o.x = (a.x + b.x) + (c.x + d.x);
  o.y = (a.y + b.y) + (c.y + d.y);
  o.z = (a.z + b.z) + (c.z + d.z);
  o.w = (a.w + b.w) + (c.w + d.w);
  if (ADDC) {
    const float4 e = *(const float4*)(out + i);
    o.x += e.x; o.y += e.y; o.z += e.z; o.w += e.w;
  }
  *(float4*)(out + i) = o;
}

// Swizzle (proven conflict-free R7): LDS linear for global_load_lds; global SOURCE
// chunk permuted csrc = chunk ^ ((row>>1)&3); reader slot = ks ^ ((lr>>1)&3).

// ---------------- 128x128 bf16 MFMA GEMM, ring-3 (decode + logits only) ----------------
template<bool ADDC>
__global__ __launch_bounds__(256)
void mgemm2_kernel(const u16* __restrict__ A, const u16* __restrict__ Bm,
                   const float* __restrict__ Cin, float* __restrict__ Cout,
                   int M, int N, int Astride, int AW, int BW, int Bstride, int K2) {
  __shared__ __align__(16) char lds[49152];
  const int tid = threadIdx.x;
  const int lane = tid & 63, wv = tid >> 6;
  const int wm = wv >> 1, wn = wv & 1;
  const int lr = lane & 15, ks = lane >> 4;
  const int rs3 = (lr >> 1) & 3;

  const int gx = gridDim.x;
  const int nwg = gx * gridDim.y;
  int flat = blockIdx.y * gx + blockIdx.x;
  flat = (flat & 7) * (nwg >> 3) + (flat >> 3);
  const int bn = flat % gx, bm = flat / gx;

  f32x4 acc[4][4];
  #pragma unroll
  for (int i = 0; i < 4; ++i)
    #pragma unroll
    for (int j = 0; j < 4; ++j) acc[i][j] = (f32x4){0.f, 0.f, 0.f, 0.f};

  const size_t am0 = (size_t)bm * 128, bn0 = (size_t)bn * 128;

#define STAGE(bufbase, k0) do {                                                  \
    const int aoff_ = ((k0) >= AW) ? (k0) - AW : (k0);                           \
    const int boff_ = ((k0) >= BW) ? (k0) - BW : (k0);                           \
    _Pragma("unroll")                                                            \
    for (int c_ = 0; c_ < 2; ++c_) {                                             \
      const int bo_ = c_*4096 + wv*1024 + lane*16;                               \
      const int row_ = bo_ >> 6;                                                 \
      const int csrc_ = ((bo_ >> 4) & 3) ^ ((row_ >> 1) & 3);                    \
      gload16((const char*)A + ((am0 + row_) * (size_t)Astride + aoff_ + csrc_*8) * 2, \
              lds + (bufbase) + c_*4096 + wv*1024);                              \
      gload16((const char*)Bm + ((bn0 + row_) * (size_t)Bstride + boff_ + csrc_*8) * 2, \
              lds + (bufbase) + 8192 + c_*4096 + wv*1024);                       \
    }                                                                            \
  } while (0)

  const int nt = K2 >> 5;
  STAGE(0, 0);
  if (nt > 1) STAGE(16384, 32);
  int bc = 0;
  for (int t = 0; t < nt; ++t) {
    if (t + 2 < nt) {
      int bs = bc + 2; if (bs >= 3) bs -= 3;
      STAGE(bs * 16384, (t + 2) << 5);
      asm volatile("s_waitcnt vmcnt(8)\n\ts_barrier" ::: "memory");
    } else if (t + 1 < nt) {
      asm volatile("s_waitcnt vmcnt(4)\n\ts_barrier" ::: "memory");
    } else {
      asm volatile("s_waitcnt vmcnt(0)\n\ts_barrier" ::: "memory");
    }
    const char* la = lds + bc * 16384;
    const char* lb = la + 8192;
    short8 af[4], bf[4];
    #pragma unroll
    for (int f = 0; f < 4; ++f) {
      af[f] = *(const short8*)(la + (wm*64 + f*16 + lr)*64 + ((ks ^ rs3) * 16));
      bf[f] = *(const short8*)(lb + (wn*64 + f*16 + lr)*64 + ((ks ^ rs3) * 16));
    }
    #pragma unroll
    for (int i = 0; i < 4; ++i)
      #pragma unroll
      for (int j = 0; j < 4; ++j)
        acc[i][j] = __builtin_amdgcn_mfma_f32_16x16x32_bf16(af[i], bf[j], acc[i][j], 0, 0, 0);
    asm volatile("s_barrier" ::: "memory");
    bc = bc + 1; if (bc >= 3) bc = 0;
  }
#undef STAGE

  const int col0 = bn*128 + wn*64 + lr;
  #pragma unroll
  for (int i = 0; i < 4; ++i)
    #pragma unroll
    for (int j = 0; j < 4; ++j) {
      const size_t rbase = (size_t)(bm*128 + wm*64 + i*16 + ks*4);
      #pragma unroll
      for (int r = 0; r < 4; ++r) {
        const size_t idx = (rbase + r) * (size_t)N + col0 + j*16;
        float v = acc[i][j][r];
        if (ADDC) v += Cin[idx];
        Cout[idx] = v;
      }
    }
}

// ---------------- 256x256 bf16 MFMA GEMM: 8-PHASE (all layer GEMMs; split-K) ----------
__global__ __launch_bounds__(512)
void mgemm3_kernel(const u16* __restrict__ A, const u16* __restrict__ Bm,
                   float* __restrict__ Cout, int M, int N, int Astride, int AW,
                   int Bstride, int KC) {
  __shared__ __align__(16) char lds[131072];
  const int tid = threadIdx.x;
  const int lane = tid & 63, wv = tid >> 6;
  const int wm = wv >> 2, wn = wv & 3;
  const int lr = lane & 15, ks = lane >> 4;
  const int rs3 = (lr >> 1) & 3;

  const int gx = gridDim.x;
  const int nwg = gx * gridDim.y;
  int flat = blockIdx.y * gx + blockIdx.x;
  flat = (flat & 7) * (nwg >> 3) + (flat >> 3);
  const int bn = flat % gx, bm = flat / gx;
  const int k0base = blockIdx.z * KC;
  Cout += (size_t)blockIdx.z * ((size_t)M * N);

  f32x4 acc[2][2][4][2];
  #pragma unroll
  for (int a0 = 0; a0 < 2; ++a0)
    #pragma unroll
    for (int a1 = 0; a1 < 2; ++a1)
      #pragma unroll
      for (int a2 = 0; a2 < 4; ++a2)
        #pragma unroll
        for (int a3 = 0; a3 < 2; ++a3)
          acc[a0][a1][a2][a3] = (f32x4){0.f, 0.f, 0.f, 0.f};

  const size_t am0 = (size_t)bm * 256, bn0 = (size_t)bn * 256;
  short8 af[2][4];
  short8 bf[2][2][2];

#define STG_U(ISB, TILE, HALF) do {                                               \
    const int tk_ = k0base + (TILE) * 64;                                         \
    const int aof_ = (ISB) ? tk_ : ((tk_ >= AW) ? tk_ - AW : tk_);                \
    _Pragma("unroll")                                                             \
    for (int kk_ = 0; kk_ < 2; ++kk_) {                                           \
      const int fl_ = wv*1024 + lane*16;                                          \
      const int row_ = (HALF)*128 + (fl_ >> 6);                                   \
      const int csrc_ = ((fl_ >> 4) & 3) ^ ((row_ >> 1) & 3);                     \
      const u16* gp_ = (ISB)                                                      \
        ? (Bm + (bn0 + row_) * (size_t)Bstride + tk_ + kk_*32 + csrc_*8)          \
        : (A  + (am0 + row_) * (size_t)Astride + aof_ + kk_*32 + csrc_*8);        \
      gload16(gp_, lds + ((ISB)?65536:0) + ((TILE)&1)*32768 + kk_*16384 + fl_ + (HALF)*8192); \
    }                                                                             \
  } while (0)

#define PHASE(D_, IH, JH, RA, RB, SISB, STILE, SHALF, SVALID) do {                \
    if (lastit) asm volatile("s_waitcnt vmcnt(0)" ::: "memory");                  \
    else        asm volatile("s_waitcnt vmcnt(6)" ::: "memory");                  \
    if (RA) {                                                                     \
      _Pragma("unroll")                                                           \
      for (int kk = 0; kk < 2; ++kk)                                              \
        _Pragma("unroll")                                                         \
        for (int i = 0; i < 4; ++i)                                               \
          af[kk][i] = *(const short8*)(lds + (D_)*32768 + kk*16384 +              \
              ((IH)*128 + wm*64 + i*16 + lr)*64 + ((ks ^ rs3)*16));               \
    }                                                                             \
    if (RB) {                                                                     \
      _Pragma("unroll")                                                           \
      for (int kk = 0; kk < 2; ++kk)                                              \
        _Pragma("unroll")                                                         \
        for (int j = 0; j < 2; ++j)                                               \
          bf[JH][kk][j] = *(const short8*)(lds + 65536 + (D_)*32768 + kk*16384 +  \
              ((JH)*128 + wn*32 + j*16 + lr)*64 + ((ks ^ rs3)*16));               \
    }                                                                             \
    if (SVALID) STG_U(SISB, STILE, SHALF);                                        \
    asm volatile("s_barrier" ::: "memory");                                       \
    asm volatile("s_waitcnt lgkmcnt(0)" ::: "memory");                            \
    __builtin_amdgcn_sched_barrier(0);                                            \
    __builtin_amdgcn_s_setprio(1);                                                \
    _Pragma("unroll")                                                             \
    for (int i = 0; i < 4; ++i)                                                   \
      _Pragma("unroll")                                                           \
      for (int j = 0; j < 2; ++j)                                                 \
        _Pragma("unroll")                                                         \
        for (int kk = 0; kk < 2; ++kk)                                            \
          acc[IH][JH][i][j] = __builtin_amdgcn_mfma_f32_16x16x32_bf16(            \
              af[kk][i], bf[JH][kk][j], acc[IH][JH][i][j], 0, 0, 0);              \
    __builtin_amdgcn_s_setprio(0);                                                \
    asm volatile("s_barrier" ::: "memory");                                       \
  } while (0)

  const int nt2 = KC >> 6;
  const int niter = nt2 >> 1;
  STG_U(0, 0, 0); STG_U(1, 0, 0); STG_U(0, 0, 1); STG_U(1, 0, 1);
  STG_U(0, 1, 0); STG_U(1, 1, 0);

  for (int t = 0; t < niter; ++t) {
    const int t1 = 2*t + 1, t2 = 2*t + 2, t3 = 2*t + 3;
    const bool s2 = (t2 < nt2), s3 = (t3 < nt2);
    const bool lastit = (t + 1 >= niter);
    PHASE(0, 0, 0, 1, 1, 0, t1, 1, true);
    PHASE(0, 0, 1, 0, 1, 1, t1, 1, true);
    PHASE(0, 1, 0, 1, 0, 0, t2, 0, s2);
    PHASE(0, 1, 1, 0, 0, 1, t2, 0, s2);
    PHASE(1, 0, 0, 1, 1, 0, t2, 1, s2);
    PHASE(1, 0, 1, 0, 1, 1, t2, 1, s2);
    PHASE(1, 1, 0, 1, 0, 0, t3, 0, s3);
    PHASE(1, 1, 1, 0, 0, 1, t3, 0, s3);
  }
#undef PHASE
#undef STG_U

  #pragma unroll
  for (int ih = 0; ih < 2; ++ih)
    #pragma unroll
    for (int jh = 0; jh < 2; ++jh) {
      const int col0 = bn*256 + jh*128 + wn*32 + lr;
      #pragma unroll
      for (int i = 0; i < 4; ++i)
        #pragma unroll
        for (int j = 0; j < 2; ++j) {
          const size_t rbase = (size_t)(bm*256 + ih*128 + wm*64 + i*16 + ks*4);
          #pragma unroll
          for (int r = 0; r < 4; ++r)
            Cout[(rbase + r) * (size_t)N + col0 + j*16] = acc[ih][jh][i][j][r];
        }
    }
}

// ---------------- PonderNet halting + stream write-back (wpost folded) ----------------
__global__ __launch_bounds__(256)
void halt_kernel(const float* __restrict__ y, const float* __restrict__ h_mix,
                 const float* __restrict__ wpost, const float* __restrict__ hw,
                 const float* __restrict__ hb, float* __restrict__ h_out,
                 float* __restrict__ ek_acc) {
  const int sb = blockIdx.x;
  const int b = sb % B, s = sb / B;
  const int tid = threadIdx.x;
  __shared__ float red[256];
  __shared__ float lam_s[KF];
  __shared__ float pk_s[KF];
  __shared__ float sw[4];
  if (tid == 0) {
    float a[4];
    float mx = fmaxf(fmaxf(wpost[0], wpost[1]), fmaxf(wpost[2], wpost[3]));
    float sm = 0.f;
    for (int i = 0; i < 4; ++i) { a[i] = expf(wpost[i] - mx); sm += a[i]; }
    for (int i = 0; i < 4; ++i) sw[i] = a[i] / sm;
  }

  for (int k = 0; k < KF; ++k) {
    const float* yr = y + ((size_t)(s*KF + k) * B + b) * D;
    float p = 0.f;
    for (int d = tid; d < D; d += 256) p = fmaf(yr[d], hw[d], p);
    red[tid] = p; __syncthreads();
    for (int off = 128; off > 0; off >>= 1) {
      if (tid < off) red[tid] += red[tid + off];
      __syncthreads();
    }
    if (tid == 0) lam_s[k] = 1.f / (1.f + expf(-(red[0] + hb[0])));
    __syncthreads();
  }
  if (tid == 0) {
    float keep = 1.f, sum = 0.f, pk[KF];
    #pragma unroll
    for (int k = 0; k < KF; ++k) { pk[k] = lam_s[k] * keep; keep *= (1.f - lam_s[k]); sum += pk[k]; }
    pk[KF-1] += 1.f - sum;
    float ek = 0.f;
    #pragma unroll
    for (int k = 0; k < KF; ++k) { ek += pk[k] * (float)(k + 1); pk_s[k] = pk[k]; }
    atomicAdd(ek_acc, ek);
  }
  __syncthreads();
  for (int d = tid; d < D; d += 256) {
    float yt = 0.f;
    #pragma unroll
    for (int k = 0; k < KF; ++k)
      yt = fmaf(pk_s[k], y[((size_t)(s*KF + k) * B + b) * D + d], yt);
    #pragma unroll
    for (int n = 0; n < NS; ++n) {
      const size_t off = ((size_t)sb * NS + n) * D + d;
      h_out[off] = h_mix[off] + sw[n] * yt;
    }
  }
}

// ---------------- decode: stream-collapse + rmsnorm ----------------
__global__ __launch_bounds__(256)
void collnorm_kernel(const float* __restrict__ h, const float* __restrict__ w,
                     float* __restrict__ xn) {
  const int sb = blockIdx.x, tid = threadIdx.x;
  __shared__ float red[256];
  float vals[4]; float ss = 0.f;
  #pragma unroll
  for (int i = 0; i < 4; ++i) {
    const int d = tid + i*256;
    const float* hp = h + (size_t)sb * NS * D + d;
    float m = 0.25f * (hp[0] + hp[D] + hp[2*D] + hp[3*D]);
    vals[i] = m; ss += m*m;
  }
  red[tid] = ss; __syncthreads();
  for (int off = 128; off > 0; off >>= 1) { if (tid < off) red[tid] += red[tid + off]; __syncthreads(); }
  const float inv = 1.f / sqrtf(red[0] * (1.f/(float)D) + 1e-6f);
  #pragma unroll
  for (int i = 0; i < 4; ++i) {
    const int d = tid + i*256;
    xn[(size_t)sb * D + d] = vals[i] * w[d] * inv;
  }
}

// ---------------- decode output PLIF -> spike counts (exact bf16 ints) ----------------
__global__ __launch_bounds__(256)
void dplif_kernel(const float* __restrict__ xn, const float* __restrict__ beta,
                  const float* __restrict__ vth, u16* __restrict__ dec) {
  const int idx = blockIdx.x * 256 + threadIdx.x;
  const int b = idx / D, d = idx % D;
  const float be = beta[d], vt = vth[d], omb = 1.f - be;
  float v = 0.f;
  for (int s = 0; s < S; ++s) {
    const float xv = xn[((size_t)s * B + b) * D + d];
    float cnt = 0.f;
    #pragma unroll
    for (int k = 0; k < KF; ++k) {
      v = fmaf(be, v, omb * xv);
      if (v >= vt) { v -= vt; cnt += 1.f; }
    }
    const __hip_bfloat16 hb_ = __float2bfloat16(cnt);
    dec[((size_t)b * S + s) * D + d] = *(const u16*)&hb_;
  }
}

// ---------------- lateral inhibition (in-place, with bias add) ----------------
__global__ __launch_bounds__(256)
void li_kernel(float* __restrict__ hh, const float* __restrict__ bias,
               const float* __restrict__ w) {
  const int r = blockIdx.x, tid = threadIdx.x;
  __shared__ float red[256];
  float* row = hh + (size_t)r * D;
  float v[4]; float sm = 0.f;
  #pragma unroll
  for (int i = 0; i < 4; ++i) { const int d = tid + i*256; v[i] = row[d] + bias[d]; sm += v[i]; }
  red[tid] = sm; __syncthreads();
  for (int off = 128; off > 0; off >>= 1) { if (tid < off) red[tid] += red[tid + off]; __syncthreads(); }
  const float mean = red[0] * (1.f/(float)D);
  __syncthreads();
  float ss = 0.f;
  #pragma unroll
  for (int i = 0; i < 4; ++i) { v[i] -= mean; ss += v[i]*v[i]; }
  red[tid] = ss; __syncthreads();
  for (int off = 128; off > 0; off >>= 1) { if (tid < off) red[tid] += red[tid + off]; __syncthreads(); }
  const float inv = 1.f / sqrtf(red[0] * (1.f/(float)D) + 1e-6f);
  #pragma unroll
  for (int i = 0; i < 4; ++i) { const int d = tid + i*256; row[d] = w[d] * v[i] * inv; }
}

// ---------------- hi/lo split of a fp32 activation matrix [M][Kd] -> [M][2Kd] ----------------
__global__ __launch_bounds__(256)
void split_kernel(const float* __restrict__ X, u16* __restrict__ xs, int Kd) {
  const size_t idx = (size_t)blockIdx.x * 256 + threadIdx.x;
  const int k = (int)(idx % Kd);
  const size_t n = idx / Kd;
  const float v = X[idx];
  const __hip_bfloat16 h = __float2bfloat16(v);
  const size_t off = n * (2*Kd) + k;
  xs[off] = *(const u16*)&h;
  const __hip_bfloat16 lo = __float2bfloat16(v - __bfloat162float(h));
  xs[off + Kd] = *(const u16*)&lo;
}

// ---------------- ponder / ekf tail ----------------
__global__ void finalize_kernel(const float* __restrict__ ek_acc, float* __restrict__ tail) {
  if (threadIdx.x != 0 || blockIdx.x != 0) return;
  float ponder = 0.f, ekf = 0.f;
  for (int l = 0; l < LNUM; ++l) {
    float ek = ek_acc[l] * (1.f/(float)(S*B));
    ponder += ek;
    ekf += fmaxf(0.f - ek, 0.f);
  }
  tail[0] = ponder * (1.f/(float)LNUM);
  tail[1] = ekf * (1.f/(float)LNUM);
}

extern "C" void kernel_launch(void* const* d_in, const int* in_sizes, int n_in,
                              void* d_out, int out_size, void* d_ws, size_t ws_size,
                              hipStream_t stream) {
  const int*   tok       = (const int*)  d_in[0];
  const float* embed     = (const float*)d_in[1];
  const float* norm_w    = (const float*)d_in[2];
  const float* decode_W  = (const float*)d_in[3];
  const float* decode_b  = (const float*)d_in[4];
  const float* out_norm  = (const float*)d_in[5];
  const float* beta_out  = (const float*)d_in[6];
  const float* vth_out   = (const float*)d_in[7];
  const float* H_logits  = (const float*)d_in[8];
  const float* w_pre     = (const float*)d_in[9];
  const float* w_post    = (const float*)d_in[10];
  const float* beta_in1  = (const float*)d_in[11];
  const float* vth_in1   = (const float*)d_in[12];
  const float* W_in      = (const float*)d_in[13];
  const float* beta_h    = (const float*)d_in[14];
  const float* vth_h     = (const float*)d_in[15];
  const float* W_out     = (const float*)d_in[16];
  const float* beta_in2  = (const float*)d_in[17];
  const float* vth_in2   = (const float*)d_in[18];
  const float* W_gate    = (const float*)d_in[19];
  const float* beta_gate = (const float*)d_in[20];
  const float* vth_gate  = (const float*)d_in[21];
  const float* W_up      = (const float*)d_in[22];
  const float* beta_up   = (const float*)d_in[23];
  const float* vth_up    = (const float*)d_in[24];
  const float* W_down    = (const float*)d_in[25];
  const float* halt_w    = (const float*)d_in[26];
  const float* halt_b    = (const float*)d_in[27];
  float* out = (float*)d_out;

  float* ws = (float*)d_ws;
  size_t o = 0;
  float* ek_acc = ws + o; o += 16;
  float* h_cur = ws + o; o += (size_t)S*B*NS*D;
  float* h_mix = ws + o; o += (size_t)S*B*NS*D;
  float* xbuf  = ws + o; o += (size_t)S*B*D;
  float* y_blk = ws + o; o += (size_t)TB*D;
  float* zbig  = ws + o; o += (size_t)TB*2*DFF;        // z_h / z12 / split-K partials
  u16*   spb   = (u16*)(ws + o); o += (size_t)TB*ND/2;
  u16*   s1b   = (u16*)(ws + o); o += (size_t)TB*D/2;
  u16*   s2b   = (u16*)(ws + o); o += (size_t)TB*D/2;
  float* xn    = ws + o; o += (size_t)S*B*D;
  u16*   decb  = (u16*)(ws + o); o += (size_t)B*S*D/2;
  float* hh    = ws + o; o += (size_t)B*S*D;
  u16*   wt    = (u16*)(ws + o); o += (size_t)(2*DFF)*D;
  if (ws_size < o * sizeof(float)) return;

  hipMemsetAsync(ek_acc, 0, 3 * sizeof(float), stream);

  gather_kernel<<<(S*B*NS*D)/256, 256, 0, stream>>>(tok, embed, h_cur);

  for (int l = 0; l < LNUM; ++l) {
    mix_kernel<<<(S*B*D)/256, 256, 0, stream>>>(h_cur, H_logits + l*16, w_pre + l*4,
                                                h_mix, xbuf);
    plif_kernel<true,false><<<(B*D)/256, 256, 0, stream>>>(
        xbuf, nullptr, beta_in1 + l*D, vth_in1 + l*D, s1b, D);

    // z_h = s1 @ W_in (vth_in1 folded): 8-phase 256^2
    { dim3 gp(ND/64, D/64);
      prep_t_kernel<<<gp, 256, 0, stream>>>(W_in + (size_t)l*D*ND, vth_in1 + l*D, nullptr, 1.f,
                                            wt, D, ND); }
    { dim3 g(ND/256, TB/256, 1);
      mgemm3_kernel<<<g, 512, 0, stream>>>(s1b, wt, zbig, TB, ND, D, D, 2*D, 2*D); }
    plif_kernel<false,false><<<(B*ND)/256, 256, 0, stream>>>(
        zbig, nullptr, beta_h + l*ND, vth_h + l*ND, spb, ND);

    // y_blk = sh @ W_out (vth_h folded): 8-phase split-K x4 -> reduce
    { dim3 gp(D/64, ND/64);
      prep_t_kernel<<<gp, 256, 0, stream>>>(W_out + (size_t)l*ND*D, vth_h + l*ND, nullptr, 1.f,
                                            wt, ND, D); }
    { dim3 g(D/256, TB/256, 4);   // KC = 2048
      mgemm3_kernel<<<g, 512, 0, stream>>>(spb, wt, zbig, TB, D, ND, ND, 2*ND, 2048); }
    reduce4_kernel<false><<<(TB*D)/1024, 256, 0, stream>>>(y_blk, zbig, (size_t)TB*D);
    plif_kernel<true,true><<<(B*D)/256, 256, 0, stream>>>(
        xbuf, y_blk, beta_in2 + l*D, vth_in2 + l*D, s2b, D);

    // z12 = s2 @ [W_gate | W_up] (vth_in2 folded): 8-phase 256^2 (R11-proven)
    { dim3 gp(DFF/64, D/64, 2);
      prep_t2_kernel<<<gp, 256, 0, stream>>>(W_gate + (size_t)l*D*DFF, W_up + (size_t)l*D*DFF,
                                             vth_in2 + l*D, wt, wt + (size_t)DFF*2*D, D, DFF); }
    { dim3 g((2*DFF)/256, TB/256, 1);
      mgemm3_kernel<<<g, 512, 0, stream>>>(s2b, wt, zbig, TB, 2*DFF, D, D, 2*D, 2*D); }
    plif_gu_kernel<<<(B*DFF)/256, 256, 0, stream>>>(
        zbig, beta_gate + l*DFF, vth_gate + l*DFF, beta_up + l*DFF, vth_up + l*DFF, spb);

    // y_blk += (g*u) @ W_down (vth_g*vth_u folded): 8-phase split-K x4 -> reduce(+=)
    { dim3 gp(D/64, DFF/64);
      prep_t_kernel<<<gp, 256, 0, stream>>>(W_down + (size_t)l*DFF*D, vth_gate + l*DFF,
                                            vth_up + l*DFF, 1.f, wt, DFF, D); }
    { dim3 g(D/256, TB/256, 4);   // KC = 1536
      mgemm3_kernel<<<g, 512, 0, stream>>>(spb, wt, zbig, TB, D, DFF, DFF, 2*DFF, 1536); }
    reduce4_kernel<true><<<(TB*D)/1024, 256, 0, stream>>>(y_blk, zbig, (size_t)TB*D);
    halt_kernel<<<S*B, 256, 0, stream>>>(y_blk, h_mix, w_post + l*4, halt_w + l*D,
                                         halt_b + l, h_cur, ek_acc + l);
  }

  collnorm_kernel<<<S*B, 256, 0, stream>>>(h_cur, out_norm, xn);
  dplif_kernel<<<(B*D)/256, 256, 0, stream>>>(xn, beta_out, vth_out, decb);

  // hh = dec @ (decode_W * vth_out/8)^T: 128^2 kernel
  prep_nt_kernel<<<(D*D)/256, 256, 0, stream>>>(decode_W, vth_out, 0.125f, wt, D);
  { dim3 g(D/128, (B*S)/128);
    mgemm2_kernel<false><<<g, 256, 0, stream>>>(decb, wt, nullptr, hh, B*S, D,
                                                D, D, 2*D, 2*D, 2*D); }
  li_kernel<<<B*S, 256, 0, stream>>>(hh, decode_b, norm_w);

  // logits = hh @ embed^T, 3-term split: K2=3D loop over B [6144][2048] (Bstride=2D)
  u16* hh_c  = (u16*)(zbig + 6600000);
  u16* emb_c = (u16*)zbig;
  split_kernel<<<(B*S*D)/256, 256, 0, stream>>>(hh, hh_c, D);
  prep_nt_kernel<<<(VOCABSZ*D)/256, 256, 0, stream>>>(embed, nullptr, 1.f, emb_c, D);
  { dim3 g(VOCABSZ/128, (B*S)/128);
    mgemm2_kernel<false><<<g, 256, 0, stream>>>(hh_c, emb_c, nullptr, out, B*S, VOCABSZ,
                                                2*D, D, 2*D, 2*D, 3*D); }
  finalize_kernel<<<1, 1, 0, stream>>>(ek_acc, out + (out_size - 2));
}

// Round 15
// 1959.296 us; speedup vs baseline: 1.0676x; 1.0676x over previous
//
#include <hip/hip_runtime.h>
#include <hip/hip_bf16.h>

#define B 4
#define S 128
#define D 1024
#define NS 4
#define KF 8
#define LNUM 3
#define DFF 3072
#define ND 4096
#define T 1024          // S*KF
#define TB 4096         // T*B
#define VOCABSZ 6144
#define SINKIT 20

typedef unsigned short u16;
typedef __attribute__((ext_vector_type(8))) short short8;
typedef __attribute__((ext_vector_type(4))) float f32x4;

__device__ __forceinline__ void gload16(const void* g, void* l) {
  __builtin_amdgcn_global_load_lds(
      (const __attribute__((address_space(1))) void*)g,
      (__attribute__((address_space(3))) void*)l, 16, 0, 0);
}

// ---------------- sinkhorn + softmax(w_pre/w_post) ----------------
__global__ void sink_kernel(const float* __restrict__ Hl, const float* __restrict__ wpre,
                            const float* __restrict__ wpost, float* __restrict__ prm) {
  if (threadIdx.x != 0 || blockIdx.x != 0) return;
  float M[16];
  for (int i = 0; i < 16; ++i) M[i] = expf(Hl[i]);
  for (int it = 0; it < SINKIT; ++it) {
    for (int m = 0; m < 4; ++m) {
      float s = M[m*4+0] + M[m*4+1] + M[m*4+2] + M[m*4+3];
      for (int n = 0; n < 4; ++n) M[m*4+n] /= s;
    }
    for (int n = 0; n < 4; ++n) {
      float s = M[0*4+n] + M[1*4+n] + M[2*4+n] + M[3*4+n];
      for (int m = 0; m < 4; ++m) M[m*4+n] /= s;
    }
  }
  for (int i = 0; i < 16; ++i) prm[i] = M[i];
  float a[4], mx, sm;
  mx = fmaxf(fmaxf(wpre[0], wpre[1]), fmaxf(wpre[2], wpre[3]));
  sm = 0.f; for (int i = 0; i < 4; ++i) { a[i] = expf(wpre[i] - mx); sm += a[i]; }
  for (int i = 0; i < 4; ++i) prm[16+i] = a[i] / sm;
  mx = fmaxf(fmaxf(wpost[0], wpost[1]), fmaxf(wpost[2], wpost[3]));
  sm = 0.f; for (int i = 0; i < 4; ++i) { a[i] = expf(wpost[i] - mx); sm += a[i]; }
  for (int i = 0; i < 4; ++i) prm[20+i] = a[i] / sm;
}

// ---------------- embed gather ----------------
__global__ __launch_bounds__(256)
void gather_kernel(const int* __restrict__ tok, const float* __restrict__ embed,
                   float* __restrict__ h) {
  const int idx = blockIdx.x * 256 + threadIdx.x;
  const int d   = idx % D;
  const int sbn = idx / D;
  const int sb  = sbn / NS;
  const int b   = sb % B, s = sb / B;
  h[idx] = embed[(size_t)tok[b*S + s] * D + d];
}

// ---------------- stream mix ----------------
__global__ __launch_bounds__(256)
void mix_kernel(const float* __restrict__ h, const float* __restrict__ P,
                float* __restrict__ h_mix, float* __restrict__ x) {
  const int idx = blockIdx.x * 256 + threadIdx.x;
  const int d = idx % D, sb = idx / D;
  const float* hp = h + (size_t)sb * NS * D + d;
  const float h0 = hp[0], h1 = hp[D], h2 = hp[2*D], h3 = hp[3*D];
  float xv = 0.f;
  #pragma unroll
  for (int m = 0; m < 4; ++m) {
    float hm = P[m*4+0]*h0 + P[m*4+1]*h1 + P[m*4+2]*h2 + P[m*4+3]*h3;
    h_mix[(size_t)sb * NS * D + m*D + d] = hm;
    xv = fmaf(P[16+m], hm, xv);
  }
  x[idx] = xv;
}

// ---------------- PLIF scan -> binary bf16 spikes (manual reg pipeline, PF=32) --------
template<bool R1, bool A2>
__global__ __launch_bounds__(256)
void plif_kernel(const float* __restrict__ z1, const float* __restrict__ z2,
                 const float* __restrict__ beta, const float* __restrict__ vth,
                 u16* __restrict__ outp, int C) {
  const int idx = blockIdx.x * 256 + threadIdx.x;
  const int c = idx % C;
  const int stride = B * C;
  const float be = beta[c], vt = vth[c], omb = 1.f - be;
  float v = 0.f;
  constexpr int PF = 32;
  float xA[PF], yA[PF], xB[PF], yB[PF];

#define PLOAD(xa, ya, tb) do {                                               \
    if (R1) {                                                                \
      _Pragma("unroll")                                                      \
      for (int i = 0; i < PF/8; ++i)                                         \
        xa[i] = z1[(size_t)((tb)/8 + i) * stride + idx];                     \
    } else {                                                                 \
      _Pragma("unroll")                                                      \
      for (int i = 0; i < PF; ++i)                                           \
        xa[i] = z1[(size_t)((tb) + i) * stride + idx];                       \
    }                                                                        \
    if (A2) {                                                                \
      _Pragma("unroll")                                                      \
      for (int i = 0; i < PF; ++i)                                           \
        ya[i] = z2[(size_t)((tb) + i) * stride + idx];                       \
    }                                                                        \
  } while (0)

#define PCOMP(xa, ya, tb) do {                                               \
    _Pragma("unroll")                                                        \
    for (int i = 0; i < PF; ++i) {                                           \
      float xt = R1 ? xa[i >> 3] : xa[i];                                    \
      if (A2) xt += ya[i];                                                   \
      v = fmaf(be, v, omb * xt);                                             \
      const bool sp = (v >= vt);                                             \
      if (sp) v -= vt;                                                       \
      outp[(size_t)((tb) + i) * stride + idx] = sp ? (u16)0x3F80 : (u16)0;   \
    }                                                                        \
  } while (0)

  PLOAD(xA, yA, 0);
  for (int tb = 0; tb < T; tb += 2*PF) {
    PLOAD(xB, yB, tb + PF);
    PCOMP(xA, yA, tb);
    if (tb + 2*PF < T) PLOAD(xA, yA, tb + 2*PF);
    PCOMP(xB, yB, tb + PF);
  }
#undef PLOAD
#undef PCOMP
}

// ---------------- fused gate+up PLIF from fused z12 [t][b][6144] ----------------
__global__ __launch_bounds__(256)
void plif_gu_kernel(const float* __restrict__ z12,
                    const float* __restrict__ bg, const float* __restrict__ vg_,
                    const float* __restrict__ bu, const float* __restrict__ vu_,
                    u16* __restrict__ outp) {
  const int idx = blockIdx.x * 256 + threadIdx.x;   // over B*DFF
  const int c = idx % DFF, b = idx / DFF;
  const float beg = bg[c], vtg = vg_[c], beu = bu[c], vtu = vu_[c];
  const float og = 1.f - beg, ou = 1.f - beu;
  float vg = 0.f, vu = 0.f;
  constexpr int PF = 32;
  float gA[PF], uA[PF], gB[PF], uB[PF];

#define GLOAD_(ga, ua, tb) do {                                              \
    _Pragma("unroll")                                                        \
    for (int i = 0; i < PF; ++i) {                                           \
      const size_t off_ = ((size_t)((tb) + i) * B + b) * (2*DFF) + c;        \
      ga[i] = z12[off_];                                                     \
      ua[i] = z12[off_ + DFF];                                               \
    }                                                                        \
  } while (0)

#define GCOMP_(ga, ua, tb) do {                                              \
    _Pragma("unroll")                                                        \
    for (int i = 0; i < PF; ++i) {                                           \
      vg = fmaf(beg, vg, og * ga[i]);                                        \
      vu = fmaf(beu, vu, ou * ua[i]);                                        \
      const bool sg = (vg >= vtg), su = (vu >= vtu);                         \
      if (sg) vg -= vtg;                                                     \
      if (su) vu -= vtu;                                                     \
      outp[(size_t)((tb) + i) * (B*DFF) + idx] = (sg && su) ? (u16)0x3F80 : (u16)0; \
    }                                                                        \
  } while (0)

  GLOAD_(gA, uA, 0);
  for (int tb = 0; tb < T; tb += 2*PF) {
    GLOAD_(gB, uB, tb + PF);
    GCOMP_(gA, uA, tb);
    if (tb + 2*PF < T) GLOAD_(gA, uA, tb + 2*PF);
    GCOMP_(gB, uB, tb + PF);
  }
#undef GLOAD_
#undef GCOMP_
}

// ---------------- weight prep: transpose + scale + bf16 hi/lo split -> [N][2K] ----------------
__global__ __launch_bounds__(256)
void prep_t_kernel(const float* __restrict__ W, const float* __restrict__ sA,
                   const float* __restrict__ sB, float mult,
                   u16* __restrict__ wt, int Kd, int Nd) {
  __shared__ float tile[64][65];
  const int tid = threadIdx.x;
  const int bn = blockIdx.x, bk = blockIdx.y;
  const int c = tid & 63, r0 = (tid >> 6) * 16;
  #pragma unroll
  for (int i = 0; i < 16; ++i) {
    const int r = r0 + i;
    const int kg = bk*64 + r;
    float s = mult;
    if (sA) s *= sA[kg];
    if (sB) s *= sB[kg];
    tile[r][c] = W[(size_t)kg * Nd + bn*64 + c] * s;
  }
  __syncthreads();
  const int K2 = 2 * Kd;
  #pragma unroll
  for (int i = 0; i < 16; ++i) {
    const int nl = r0 + i;
    const float v = tile[c][nl];
    const __hip_bfloat16 h = __float2bfloat16(v);
    const size_t off = (size_t)(bn*64 + nl) * K2 + bk*64 + c;
    wt[off] = *(const u16*)&h;
    const __hip_bfloat16 lo = __float2bfloat16(v - __bfloat162float(h));
    wt[off + Kd] = *(const u16*)&lo;
  }
}

// ---------------- prep (no transpose): W [Nd][Kd] -> wt [Nd][2Kd] hi|lo ----------------
__global__ __launch_bounds__(256)
void prep_nt_kernel(const float* __restrict__ W, const float* __restrict__ sK, float mult,
                    u16* __restrict__ wt, int Kd) {
  const size_t idx = (size_t)blockIdx.x * 256 + threadIdx.x;
  const int k = (int)(idx % Kd);
  const size_t n = idx / Kd;
  const float v = W[idx] * mult * (sK ? sK[k] : 1.f);
  const __hip_bfloat16 h = __float2bfloat16(v);
  const size_t off = n * (2*Kd) + k;
  wt[off] = *(const u16*)&h;
  const __hip_bfloat16 lo = __float2bfloat16(v - __bfloat162float(h));
  wt[off + Kd] = *(const u16*)&lo;
}

// ---------------- deterministic 4-way partial reduce: out [=|+=] p0+p1+p2+p3 ----------------
template<bool ADDC>
__global__ __launch_bounds__(256)
void reduce4_kernel(float* __restrict__ out, const float* __restrict__ p, size_t n) {
  const size_t i = ((size_t)blockIdx.x * 256 + threadIdx.x) * 4;
  float4 a = *(const float4*)(p + i);
  float4 b = *(const float4*)(p + n + i);
  float4 c = *(const float4*)(p + 2*n + i);
  float4 d = *(const float4*)(p + 3*n + i);
  float4 o;
  o.x = (a.x + b.x) + (c.x + d.x);
  o.y = (a.y + b.y) + (c.y + d.y);
  o.z = (a.z + b.z) + (c.z + d.z);
  o.w = (a.w + b.w) + (c.w + d.w);
  if (ADDC) {
    const float4 e = *(const float4*)(out + i);
    o.x += e.x; o.y += e.y; o.z += e.z; o.w += e.w;
  }
  *(float4*)(out + i) = o;
}

// Swizzle (proven conflict-free R7): LDS linear for global_load_lds; global SOURCE
// chunk permuted csrc = chunk ^ ((row>>1)&3); reader slot = ks ^ ((lr>>1)&3).

// ---------------- 128x128 bf16 MFMA GEMM, ring-3 (decode + logits only) ----------------
template<bool ADDC>
__global__ __launch_bounds__(256)
void mgemm2_kernel(const u16* __restrict__ A, const u16* __restrict__ Bm,
                   const float* __restrict__ Cin, float* __restrict__ Cout,
                   int M, int N, int Astride, int AW, int BW, int Bstride, int K2) {
  __shared__ __align__(16) char lds[49152];   // 3 bufs x (A 8K | B 8K)
  const int tid = threadIdx.x;
  const int lane = tid & 63, wv = tid >> 6;
  const int wm = wv >> 1, wn = wv & 1;
  const int lr = lane & 15, ks = lane >> 4;
  const int rs3 = (lr >> 1) & 3;

  const int gx = gridDim.x;
  const int nwg = gx * gridDim.y;
  int flat = blockIdx.y * gx + blockIdx.x;
  flat = (flat & 7) * (nwg >> 3) + (flat >> 3);
  const int bn = flat % gx, bm = flat / gx;

  f32x4 acc[4][4];
  #pragma unroll
  for (int i = 0; i < 4; ++i)
    #pragma unroll
    for (int j = 0; j < 4; ++j) acc[i][j] = (f32x4){0.f, 0.f, 0.f, 0.f};

  const size_t am0 = (size_t)bm * 128, bn0 = (size_t)bn * 128;

#define STAGE(bufbase, k0) do {                                                  \
    const int aoff_ = ((k0) >= AW) ? (k0) - AW : (k0);                           \
    const int boff_ = ((k0) >= BW) ? (k0) - BW : (k0);                           \
    _Pragma("unroll")                                                            \
    for (int c_ = 0; c_ < 2; ++c_) {                                             \
      const int bo_ = c_*4096 + wv*1024 + lane*16;                               \
      const int row_ = bo_ >> 6;                                                 \
      const int csrc_ = ((bo_ >> 4) & 3) ^ ((row_ >> 1) & 3);                    \
      gload16((const char*)A + ((am0 + row_) * (size_t)Astride + aoff_ + csrc_*8) * 2, \
              lds + (bufbase) + c_*4096 + wv*1024);                              \
      gload16((const char*)Bm + ((bn0 + row_) * (size_t)Bstride + boff_ + csrc_*8) * 2, \
              lds + (bufbase) + 8192 + c_*4096 + wv*1024);                       \
    }                                                                            \
  } while (0)

  const int nt = K2 >> 5;
  STAGE(0, 0);
  if (nt > 1) STAGE(16384, 32);
  int bc = 0;
  for (int t = 0; t < nt; ++t) {
    if (t + 2 < nt) {
      int bs = bc + 2; if (bs >= 3) bs -= 3;
      STAGE(bs * 16384, (t + 2) << 5);
      asm volatile("s_waitcnt vmcnt(8)\n\ts_barrier" ::: "memory");
    } else if (t + 1 < nt) {
      asm volatile("s_waitcnt vmcnt(4)\n\ts_barrier" ::: "memory");
    } else {
      asm volatile("s_waitcnt vmcnt(0)\n\ts_barrier" ::: "memory");
    }
    const char* la = lds + bc * 16384;
    const char* lb = la + 8192;
    short8 af[4], bf[4];
    #pragma unroll
    for (int f = 0; f < 4; ++f) {
      af[f] = *(const short8*)(la + (wm*64 + f*16 + lr)*64 + ((ks ^ rs3) * 16));
      bf[f] = *(const short8*)(lb + (wn*64 + f*16 + lr)*64 + ((ks ^ rs3) * 16));
    }
    #pragma unroll
    for (int i = 0; i < 4; ++i)
      #pragma unroll
      for (int j = 0; j < 4; ++j)
        acc[i][j] = __builtin_amdgcn_mfma_f32_16x16x32_bf16(af[i], bf[j], acc[i][j], 0, 0, 0);
    asm volatile("s_barrier" ::: "memory");
    bc = bc + 1; if (bc >= 3) bc = 0;
  }
#undef STAGE

  const int col0 = bn*128 + wn*64 + lr;
  #pragma unroll
  for (int i = 0; i < 4; ++i)
    #pragma unroll
    for (int j = 0; j < 4; ++j) {
      const size_t rbase = (size_t)(bm*128 + wm*64 + i*16 + ks*4);
      #pragma unroll
      for (int r = 0; r < 4; ++r) {
        const size_t idx = (rbase + r) * (size_t)N + col0 + j*16;
        float v = acc[i][j][r];
        if (ADDC) v += Cin[idx];
        Cout[idx] = v;
      }
    }
}

// ---------------- 256x256 bf16 MFMA GEMM: 8-PHASE schedule (T3+T4+T5) ----------------
// Split-K capable: blockIdx.z selects K-range [z*KC, (z+1)*KC) and partial buffer
// Cout + z*M*N. gridz=1 reproduces R10 bit-identically. KC % 128 == 0.
__global__ __launch_bounds__(512)
void mgemm3_kernel(const u16* __restrict__ A, const u16* __restrict__ Bm,
                   float* __restrict__ Cout, int M, int N, int Astride, int AW,
                   int Bstride, int KC) {
  __shared__ __align__(16) char lds[131072];
  const int tid = threadIdx.x;
  const int lane = tid & 63, wv = tid >> 6;
  const int wm = wv >> 2, wn = wv & 3;
  const int lr = lane & 15, ks = lane >> 4;
  const int rs3 = (lr >> 1) & 3;

  const int gx = gridDim.x;
  const int nwg = gx * gridDim.y;
  int flat = blockIdx.y * gx + blockIdx.x;
  flat = (flat & 7) * (nwg >> 3) + (flat >> 3);
  const int bn = flat % gx, bm = flat / gx;
  const int k0base = blockIdx.z * KC;
  Cout += (size_t)blockIdx.z * ((size_t)M * N);

  f32x4 acc[2][2][4][2];
  #pragma unroll
  for (int a0 = 0; a0 < 2; ++a0)
    #pragma unroll
    for (int a1 = 0; a1 < 2; ++a1)
      #pragma unroll
      for (int a2 = 0; a2 < 4; ++a2)
        #pragma unroll
        for (int a3 = 0; a3 < 2; ++a3)
          acc[a0][a1][a2][a3] = (f32x4){0.f, 0.f, 0.f, 0.f};

  const size_t am0 = (size_t)bm * 256, bn0 = (size_t)bn * 256;
  short8 af[2][4];       // [kk][i]  current ih
  short8 bf[2][2][2];    // [jh][kk][j]

#define STG_U(ISB, TILE, HALF) do {                                               \
    const int tk_ = k0base + (TILE) * 64;                                         \
    const int aof_ = (ISB) ? tk_ : ((tk_ >= AW) ? tk_ - AW : tk_);                \
    _Pragma("unroll")                                                             \
    for (int kk_ = 0; kk_ < 2; ++kk_) {                                           \
      const int fl_ = wv*1024 + lane*16;                                          \
      const int row_ = (HALF)*128 + (fl_ >> 6);                                   \
      const int csrc_ = ((fl_ >> 4) & 3) ^ ((row_ >> 1) & 3);                     \
      const u16* gp_ = (ISB)                                                      \
        ? (Bm + (bn0 + row_) * (size_t)Bstride + tk_ + kk_*32 + csrc_*8)          \
        : (A  + (am0 + row_) * (size_t)Astride + aof_ + kk_*32 + csrc_*8);        \
      gload16(gp_, lds + ((ISB)?65536:0) + ((TILE)&1)*32768 + kk_*16384 + fl_ + (HALF)*8192); \
    }                                                                             \
  } while (0)

#define PHASE(D_, IH, JH, RA, RB, SISB, STILE, SHALF, SVALID) do {                \
    if (lastit) asm volatile("s_waitcnt vmcnt(0)" ::: "memory");                  \
    else        asm volatile("s_waitcnt vmcnt(6)" ::: "memory");                  \
    if (RA) {                                                                     \
      _Pragma("unroll")                                                           \
      for (int kk = 0; kk < 2; ++kk)                                              \
        _Pragma("unroll")                                                         \
        for (int i = 0; i < 4; ++i)                                               \
          af[kk][i] = *(const short8*)(lds + (D_)*32768 + kk*16384 +              \
              ((IH)*128 + wm*64 + i*16 + lr)*64 + ((ks ^ rs3)*16));               \
    }                                                                             \
    if (RB) {                                                                     \
      _Pragma("unroll")                                                           \
      for (int kk = 0; kk < 2; ++kk)                                              \
        _Pragma("unroll")                                                         \
        for (int j = 0; j < 2; ++j)                                               \
          bf[JH][kk][j] = *(const short8*)(lds + 65536 + (D_)*32768 + kk*16384 +  \
              ((JH)*128 + wn*32 + j*16 + lr)*64 + ((ks ^ rs3)*16));               \
    }                                                                             \
    if (SVALID) STG_U(SISB, STILE, SHALF);                                        \
    asm volatile("s_barrier" ::: "memory");                                       \
    asm volatile("s_waitcnt lgkmcnt(0)" ::: "memory");                            \
    __builtin_amdgcn_sched_barrier(0);                                            \
    __builtin_amdgcn_s_setprio(1);                                                \
    _Pragma("unroll")                                                             \
    for (int i = 0; i < 4; ++i)                                                   \
      _Pragma("unroll")                                                           \
      for (int j = 0; j < 2; ++j)                                                 \
        _Pragma("unroll")                                                         \
        for (int kk = 0; kk < 2; ++kk)                                            \
          acc[IH][JH][i][j] = __builtin_amdgcn_mfma_f32_16x16x32_bf16(            \
              af[kk][i], bf[JH][kk][j], acc[IH][JH][i][j], 0, 0, 0);              \
    __builtin_amdgcn_s_setprio(0);                                                \
    asm volatile("s_barrier" ::: "memory");                                       \
  } while (0)

  const int nt2 = KC >> 6;        // local K-64 tiles (even)
  const int niter = nt2 >> 1;
  STG_U(0, 0, 0); STG_U(1, 0, 0); STG_U(0, 0, 1); STG_U(1, 0, 1);
  STG_U(0, 1, 0); STG_U(1, 1, 0);

  for (int t = 0; t < niter; ++t) {
    const int t1 = 2*t + 1, t2 = 2*t + 2, t3 = 2*t + 3;
    const bool s2 = (t2 < nt2), s3 = (t3 < nt2);
    const bool lastit = (t + 1 >= niter);
    PHASE(0, 0, 0, 1, 1, 0, t1, 1, true);
    PHASE(0, 0, 1, 0, 1, 1, t1, 1, true);
    PHASE(0, 1, 0, 1, 0, 0, t2, 0, s2);
    PHASE(0, 1, 1, 0, 0, 1, t2, 0, s2);
    PHASE(1, 0, 0, 1, 1, 0, t2, 1, s2);
    PHASE(1, 0, 1, 0, 1, 1, t2, 1, s2);
    PHASE(1, 1, 0, 1, 0, 0, t3, 0, s3);
    PHASE(1, 1, 1, 0, 0, 1, t3, 0, s3);
  }
#undef PHASE
#undef STG_U

  #pragma unroll
  for (int ih = 0; ih < 2; ++ih)
    #pragma unroll
    for (int jh = 0; jh < 2; ++jh) {
      const int col0 = bn*256 + jh*128 + wn*32 + lr;
      #pragma unroll
      for (int i = 0; i < 4; ++i)
        #pragma unroll
        for (int j = 0; j < 2; ++j) {
          const size_t rbase = (size_t)(bm*256 + ih*128 + wm*64 + i*16 + ks*4);
          #pragma unroll
          for (int r = 0; r < 4; ++r)
            Cout[(rbase + r) * (size_t)N + col0 + j*16] = acc[ih][jh][i][j][r];
        }
    }
}

// ---------------- PonderNet halting + stream write-back ----------------
__global__ __launch_bounds__(256)
void halt_kernel(const float* __restrict__ y, const float* __restrict__ h_mix,
                 const float* __restrict__ P, const float* __restrict__ hw,
                 const float* __restrict__ hb, float* __restrict__ h_out,
                 float* __restrict__ ek_acc) {
  const int sb = blockIdx.x;
  const int b = sb % B, s = sb / B;
  const int tid = threadIdx.x;
  __shared__ float red[256];
  __shared__ float lam_s[KF];
  __shared__ float pk_s[KF];

  for (int k = 0; k < KF; ++k) {
    const float* yr = y + ((size_t)(s*KF + k) * B + b) * D;
    float p = 0.f;
    for (int d = tid; d < D; d += 256) p = fmaf(yr[d], hw[d], p);
    red[tid] = p; __syncthreads();
    for (int off = 128; off > 0; off >>= 1) {
      if (tid < off) red[tid] += red[tid + off];
      __syncthreads();
    }
    if (tid == 0) lam_s[k] = 1.f / (1.f + expf(-(red[0] + hb[0])));
    __syncthreads();
  }
  if (tid == 0) {
    float keep = 1.f, sum = 0.f, pk[KF];
    #pragma unroll
    for (int k = 0; k < KF; ++k) { pk[k] = lam_s[k] * keep; keep *= (1.f - lam_s[k]); sum += pk[k]; }
    pk[KF-1] += 1.f - sum;
    float ek = 0.f;
    #pragma unroll
    for (int k = 0; k < KF; ++k) { ek += pk[k] * (float)(k + 1); pk_s[k] = pk[k]; }
    atomicAdd(ek_acc, ek);
  }
  __syncthreads();
  for (int d = tid; d < D; d += 256) {
    float yt = 0.f;
    #pragma unroll
    for (int k = 0; k < KF; ++k)
      yt = fmaf(pk_s[k], y[((size_t)(s*KF + k) * B + b) * D + d], yt);
    #pragma unroll
    for (int n = 0; n < NS; ++n) {
      const size_t off = ((size_t)sb * NS + n) * D + d;
      h_out[off] = h_mix[off] + P[20+n] * yt;
    }
  }
}

// ---------------- decode: stream-collapse + rmsnorm ----------------
__global__ __launch_bounds__(256)
void collnorm_kernel(const float* __restrict__ h, const float* __restrict__ w,
                     float* __restrict__ xn) {
  const int sb = blockIdx.x, tid = threadIdx.x;
  __shared__ float red[256];
  float vals[4]; float ss = 0.f;
  #pragma unroll
  for (int i = 0; i < 4; ++i) {
    const int d = tid + i*256;
    const float* hp = h + (size_t)sb * NS * D + d;
    float m = 0.25f * (hp[0] + hp[D] + hp[2*D] + hp[3*D]);
    vals[i] = m; ss += m*m;
  }
  red[tid] = ss; __syncthreads();
  for (int off = 128; off > 0; off >>= 1) { if (tid < off) red[tid] += red[tid + off]; __syncthreads(); }
  const float inv = 1.f / sqrtf(red[0] * (1.f/(float)D) + 1e-6f);
  #pragma unroll
  for (int i = 0; i < 4; ++i) {
    const int d = tid + i*256;
    xn[(size_t)sb * D + d] = vals[i] * w[d] * inv;
  }
}

// ---------------- decode output PLIF -> spike counts (exact bf16 ints) ----------------
__global__ __launch_bounds__(256)
void dplif_kernel(const float* __restrict__ xn, const float* __restrict__ beta,
                  const float* __restrict__ vth, u16* __restrict__ dec) {
  const int idx = blockIdx.x * 256 + threadIdx.x;
  const int b = idx / D, d = idx % D;
  const float be = beta[d], vt = vth[d], omb = 1.f - be;
  float v = 0.f;
  for (int s = 0; s < S; ++s) {
    const float xv = xn[((size_t)s * B + b) * D + d];
    float cnt = 0.f;
    #pragma unroll
    for (int k = 0; k < KF; ++k) {
      v = fmaf(be, v, omb * xv);
      if (v >= vt) { v -= vt; cnt += 1.f; }
    }
    const __hip_bfloat16 hb_ = __float2bfloat16(cnt);
    dec[((size_t)b * S + s) * D + d] = *(const u16*)&hb_;
  }
}

// ---------------- lateral inhibition (in-place, with bias add) ----------------
__global__ __launch_bounds__(256)
void li_kernel(float* __restrict__ hh, const float* __restrict__ bias,
               const float* __restrict__ w) {
  const int r = blockIdx.x, tid = threadIdx.x;
  __shared__ float red[256];
  float* row = hh + (size_t)r * D;
  float v[4]; float sm = 0.f;
  #pragma unroll
  for (int i = 0; i < 4; ++i) { const int d = tid + i*256; v[i] = row[d] + bias[d]; sm += v[i]; }
  red[tid] = sm; __syncthreads();
  for (int off = 128; off > 0; off >>= 1) { if (tid < off) red[tid] += red[tid + off]; __syncthreads(); }
  const float mean = red[0] * (1.f/(float)D);
  __syncthreads();
  float ss = 0.f;
  #pragma unroll
  for (int i = 0; i < 4; ++i) { v[i] -= mean; ss += v[i]*v[i]; }
  red[tid] = ss; __syncthreads();
  for (int off = 128; off > 0; off >>= 1) { if (tid < off) red[tid] += red[tid + off]; __syncthreads(); }
  const float inv = 1.f / sqrtf(red[0] * (1.f/(float)D) + 1e-6f);
  #pragma unroll
  for (int i = 0; i < 4; ++i) { const int d = tid + i*256; row[d] = w[d] * v[i] * inv; }
}

// ---------------- hi/lo split of a fp32 activation matrix [M][Kd] -> [M][2Kd] ----------------
__global__ __launch_bounds__(256)
void split_kernel(const float* __restrict__ X, u16* __restrict__ xs, int Kd) {
  const size_t idx = (size_t)blockIdx.x * 256 + threadIdx.x;
  const int k = (int)(idx % Kd);
  const size_t n = idx / Kd;
  const float v = X[idx];
  const __hip_bfloat16 h = __float2bfloat16(v);
  const size_t off = n * (2*Kd) + k;
  xs[off] = *(const u16*)&h;
  const __hip_bfloat16 lo = __float2bfloat16(v - __bfloat162float(h));
  xs[off + Kd] = *(const u16*)&lo;
}

// ---------------- ponder / ekf tail ----------------
__global__ void finalize_kernel(const float* __restrict__ ek_acc, float* __restrict__ tail) {
  if (threadIdx.x != 0 || blockIdx.x != 0) return;
  float ponder = 0.f, ekf = 0.f;
  for (int l = 0; l < LNUM; ++l) {
    float ek = ek_acc[l] * (1.f/(float)(S*B));
    ponder += ek;
    ekf += fmaxf(0.f - ek, 0.f);
  }
  tail[0] = ponder * (1.f/(float)LNUM);
  tail[1] = ekf * (1.f/(float)LNUM);
}

extern "C" void kernel_launch(void* const* d_in, const int* in_sizes, int n_in,
                              void* d_out, int out_size, void* d_ws, size_t ws_size,
                              hipStream_t stream) {
  const int*   tok       = (const int*)  d_in[0];
  const float* embed     = (const float*)d_in[1];
  const float* norm_w    = (const float*)d_in[2];
  const float* decode_W  = (const float*)d_in[3];
  const float* decode_b  = (const float*)d_in[4];
  const float* out_norm  = (const float*)d_in[5];
  const float* beta_out  = (const float*)d_in[6];
  const float* vth_out   = (const float*)d_in[7];
  const float* H_logits  = (const float*)d_in[8];
  const float* w_pre     = (const float*)d_in[9];
  const float* w_post    = (const float*)d_in[10];
  const float* beta_in1  = (const float*)d_in[11];
  const float* vth_in1   = (const float*)d_in[12];
  const float* W_in      = (const float*)d_in[13];
  const float* beta_h    = (const float*)d_in[14];
  const float* vth_h     = (const float*)d_in[15];
  const float* W_out     = (const float*)d_in[16];
  const float* beta_in2  = (const float*)d_in[17];
  const float* vth_in2   = (const float*)d_in[18];
  const float* W_gate    = (const float*)d_in[19];
  const float* beta_gate = (const float*)d_in[20];
  const float* vth_gate  = (const float*)d_in[21];
  const float* W_up      = (const float*)d_in[22];
  const float* beta_up   = (const float*)d_in[23];
  const float* vth_up    = (const float*)d_in[24];
  const float* W_down    = (const float*)d_in[25];
  const float* halt_w    = (const float*)d_in[26];
  const float* halt_b    = (const float*)d_in[27];
  float* out = (float*)d_out;

  float* ws = (float*)d_ws;
  size_t o = 0;
  float* prm   = ws + o; o += 256;
  float* h_cur = ws + o; o += (size_t)S*B*NS*D;
  float* h_mix = ws + o; o += (size_t)S*B*NS*D;
  float* xbuf  = ws + o; o += (size_t)S*B*D;
  float* y_blk = ws + o; o += (size_t)TB*D;
  float* zbig  = ws + o; o += (size_t)TB*2*DFF;        // z_h / z12 / split-K partials
  u16*   spb   = (u16*)(ws + o); o += (size_t)TB*ND/2;
  u16*   s1b   = (u16*)(ws + o); o += (size_t)TB*D/2;
  u16*   s2b   = (u16*)(ws + o); o += (size_t)TB*D/2;
  float* xn    = ws + o; o += (size_t)S*B*D;
  u16*   decb  = (u16*)(ws + o); o += (size_t)B*S*D/2;
  float* hh    = ws + o; o += (size_t)B*S*D;
  u16*   wt    = (u16*)(ws + o); o += (size_t)(2*DFF)*D;
  if (ws_size < o * sizeof(float)) return;

  float* ek_acc = prm + 96;
  hipMemsetAsync(ek_acc, 0, 3 * sizeof(float), stream);

  gather_kernel<<<(S*B*NS*D)/256, 256, 0, stream>>>(tok, embed, h_cur);

  for (int l = 0; l < LNUM; ++l) {
    float* P = prm + l*32;
    sink_kernel<<<1, 64, 0, stream>>>(H_logits + l*16, w_pre + l*4, w_post + l*4, P);
    mix_kernel<<<(S*B*D)/256, 256, 0, stream>>>(h_cur, P, h_mix, xbuf);
    plif_kernel<true,false><<<(B*D)/256, 256, 0, stream>>>(
        xbuf, nullptr, beta_in1 + l*D, vth_in1 + l*D, s1b, D);

    // z_h = s1 @ W_in (vth_in1 folded): 8-phase 256^2
    { dim3 gp(ND/64, D/64);
      prep_t_kernel<<<gp, 256, 0, stream>>>(W_in + (size_t)l*D*ND, vth_in1 + l*D, nullptr, 1.f,
                                            wt, D, ND); }
    { dim3 g(ND/256, TB/256, 1);
      mgemm3_kernel<<<g, 512, 0, stream>>>(s1b, wt, zbig, TB, ND, D, D, 2*D, 2*D); }
    plif_kernel<false,false><<<(B*ND)/256, 256, 0, stream>>>(
        zbig, nullptr, beta_h + l*ND, vth_h + l*ND, spb, ND);

    // y_blk = sh @ W_out (vth_h folded): 8-phase split-K x4 -> reduce
    { dim3 gp(D/64, ND/64);
      prep_t_kernel<<<gp, 256, 0, stream>>>(W_out + (size_t)l*ND*D, vth_h + l*ND, nullptr, 1.f,
                                            wt, ND, D); }
    { dim3 g(D/256, TB/256, 4);   // KC = 2048
      mgemm3_kernel<<<g, 512, 0, stream>>>(spb, wt, zbig, TB, D, ND, ND, 2*ND, 2048); }
    reduce4_kernel<false><<<(TB*D)/1024, 256, 0, stream>>>(y_blk, zbig, (size_t)TB*D);
    plif_kernel<true,true><<<(B*D)/256, 256, 0, stream>>>(
        xbuf, y_blk, beta_in2 + l*D, vth_in2 + l*D, s2b, D);

    // z12 = s2 @ [W_gate | W_up] (vth_in2 folded): 8-phase 256^2
    { dim3 gp(DFF/64, D/64);
      prep_t_kernel<<<gp, 256, 0, stream>>>(W_gate + (size_t)l*D*DFF, vth_in2 + l*D, nullptr, 1.f,
                                            wt, D, DFF);
      prep_t_kernel<<<gp, 256, 0, stream>>>(W_up + (size_t)l*D*DFF, vth_in2 + l*D, nullptr, 1.f,
                                            wt + (size_t)DFF*2*D, D, DFF); }
    { dim3 g((2*DFF)/256, TB/256, 1);
      mgemm3_kernel<<<g, 512, 0, stream>>>(s2b, wt, zbig, TB, 2*DFF, D, D, 2*D, 2*D); }
    plif_gu_kernel<<<(B*DFF)/256, 256, 0, stream>>>(
        zbig, beta_gate + l*DFF, vth_gate + l*DFF, beta_up + l*DFF, vth_up + l*DFF, spb);

    // y_blk += (g*u) @ W_down (vth_g*vth_u folded): 8-phase split-K x4 -> reduce(+=)
    { dim3 gp(D/64, DFF/64);
      prep_t_kernel<<<gp, 256, 0, stream>>>(W_down + (size_t)l*DFF*D, vth_gate + l*DFF,
                                            vth_up + l*DFF, 1.f, wt, DFF, D); }
    { dim3 g(D/256, TB/256, 4);   // KC = 1536
      mgemm3_kernel<<<g, 512, 0, stream>>>(spb, wt, zbig, TB, D, DFF, DFF, 2*DFF, 1536); }
    reduce4_kernel<true><<<(TB*D)/1024, 256, 0, stream>>>(y_blk, zbig, (size_t)TB*D);
    halt_kernel<<<S*B, 256, 0, stream>>>(y_blk, h_mix, P, halt_w + l*D, halt_b + l, h_cur, ek_acc + l);
  }

  collnorm_kernel<<<S*B, 256, 0, stream>>>(h_cur, out_norm, xn);
  dplif_kernel<<<(B*D)/256, 256, 0, stream>>>(xn, beta_out, vth_out, decb);

  // hh = dec @ (decode_W * vth_out/8)^T: 128^2 kernel
  prep_nt_kernel<<<(D*D)/256, 256, 0, stream>>>(decode_W, vth_out, 0.125f, wt, D);
  { dim3 g(D/128, (B*S)/128);
    mgemm2_kernel<false><<<g, 256, 0, stream>>>(decb, wt, nullptr, hh, B*S, D,
                                                D, D, 2*D, 2*D, 2*D); }
  li_kernel<<<B*S, 256, 0, stream>>>(hh, decode_b, norm_w);

  // logits = hh @ embed^T, 3-term split: K2=3D loop over B [6144][2048] (Bstride=2D)
  u16* hh_c  = (u16*)(zbig + 6600000);
  u16* emb_c = (u16*)zbig;
  split_kernel<<<(B*S*D)/256, 256, 0, stream>>>(hh, hh_c, D);
  prep_nt_kernel<<<(VOCABSZ*D)/256, 256, 0, stream>>>(embed, nullptr, 1.f, emb_c, D);
  { dim3 g(VOCABSZ/128, (B*S)/128);
    mgemm2_kernel<false><<<g, 256, 0, stream>>>(hh_c, emb_c, nullptr, out, B*S, VOCABSZ,
                                                2*D, D, 2*D, 2*D, 3*D); }
  finalize_kernel<<<1, 1, 0, stream>>>(ek_acc, out + (out_size - 2));
}